// Round 1
// baseline (248.015 us; speedup 1.0000x reference)
//
#include <hip/hip_runtime.h>

// Problem constants (match reference)
#define NF  200
#define DIN 3
#define NH  15
#define NE  30
#define NB  32768

constexpr int FC   = 25;   // features per block (200/25 = 8 f-chunks)
constexpr int BT   = 256;  // threads per block
constexpr int MB   = 2;    // batch rows per thread -> block covers 512 b
constexpr int W2LD = 32;   // padded LDS row stride for W2 (16B-aligned rows)

__global__ void nn_init(float* __restrict__ out, const float* __restrict__ b3) {
    int i = blockIdx.x * 256 + threadIdx.x;
    if (i < NB) out[i] = b3[0];
}

__global__ __launch_bounds__(BT, 2)
void nn_main(const float* __restrict__ y,  const float* __restrict__ W1,
             const float* __restrict__ b1, const float* __restrict__ W2,
             const float* __restrict__ b2, const float* __restrict__ W3,
             float* __restrict__ out) {
    __shared__ float sW1[DIN * NH];
    __shared__ float sb1[NH];
    __shared__ float sW2[NH * W2LD];
    __shared__ float sb2[NE];
    __shared__ float sW3[NE];

    const int t  = threadIdx.x;
    const int b0 = blockIdx.x * (BT * MB) + t;
    const int f0 = blockIdx.y * FC;

    float partial[MB];
#pragma unroll
    for (int m = 0; m < MB; ++m) partial[m] = 0.f;

#pragma unroll 1
    for (int fi = 0; fi < FC; ++fi) {
        const int f = f0 + fi;

        // ---- stage this feature's weights into LDS ----
        if (t < DIN * NH)          sW1[t]      = W1[f * DIN * NH + t];
        if (t < NH)                sb1[t]      = b1[f * NH + t];
        if (t < NE)                sb2[t]      = b2[f * NE + t];
        if (t >= 64 && t < 64+NE)  sW3[t - 64] = W3[f * NE + (t - 64)];
#pragma unroll
        for (int i = t; i < NH * NE; i += BT) {
            sW2[(i / NE) * W2LD + (i % NE)] = W2[f * NH * NE + i];
        }
        __syncthreads();

        // ---- load y[b, f, 0..2] ----
        float yv[MB][DIN];
#pragma unroll
        for (int m = 0; m < MB; ++m) {
            const size_t idx = (size_t)(b0 + m * BT) * (NF * DIN) + (size_t)f * DIN;
            yv[m][0] = y[idx + 0];
            yv[m][1] = y[idx + 1];
            yv[m][2] = y[idx + 2];
        }

        // ---- layer 1: h1 = relu(y @ W1 + b1) ----
        float h1[MB][NH];
#pragma unroll
        for (int h = 0; h < NH; ++h) {
            const float w0 = sW1[0 * NH + h];
            const float w1 = sW1[1 * NH + h];
            const float w2 = sW1[2 * NH + h];
            const float bb = sb1[h];
#pragma unroll
            for (int m = 0; m < MB; ++m) {
                float v = bb + yv[m][0] * w0 + yv[m][1] * w1 + yv[m][2] * w2;
                h1[m][h] = v > 0.f ? v : 0.f;
            }
        }

        // ---- layer 2: h2 = relu(h1 @ W2 + b2), fused with layer-3 partial dot ----
        float h2[MB][NE];
#pragma unroll
        for (int e = 0; e < NE; ++e) {
            const float bb = sb2[e];
#pragma unroll
            for (int m = 0; m < MB; ++m) h2[m][e] = bb;
        }
#pragma unroll
        for (int h = 0; h < NH; ++h) {
#pragma unroll
            for (int e = 0; e < NE; ++e) {
                const float w = sW2[h * W2LD + e];
#pragma unroll
                for (int m = 0; m < MB; ++m) h2[m][e] += h1[m][h] * w;
            }
        }

        // ---- layer 3 partial: sum_e relu(h2[e]) * W3[f*30+e] ----
#pragma unroll
        for (int e = 0; e < NE; ++e) {
            const float w3 = sW3[e];
#pragma unroll
            for (int m = 0; m < MB; ++m) {
                float v = h2[m][e];
                v = v > 0.f ? v : 0.f;
                partial[m] += v * w3;
            }
        }
        __syncthreads();   // before next feature overwrites LDS
    }

#pragma unroll
    for (int m = 0; m < MB; ++m) {
        atomicAdd(&out[b0 + m * BT], partial[m]);
    }
}

extern "C" void kernel_launch(void* const* d_in, const int* in_sizes, int n_in,
                              void* d_out, int out_size, void* d_ws, size_t ws_size,
                              hipStream_t stream) {
    const float* y  = (const float*)d_in[0];
    const float* W1 = (const float*)d_in[1];
    const float* b1 = (const float*)d_in[2];
    const float* W2 = (const float*)d_in[3];
    const float* b2 = (const float*)d_in[4];
    const float* W3 = (const float*)d_in[5];
    const float* b3 = (const float*)d_in[6];
    float* out = (float*)d_out;

    nn_init<<<dim3((NB + 255) / 256), dim3(256), 0, stream>>>(out, b3);
    nn_main<<<dim3(NB / (BT * MB), NF / FC), dim3(BT), 0, stream>>>(
        y, W1, b1, W2, b2, W3, out);
}

// Round 2
// 156.811 us; speedup vs baseline: 1.5816x; 1.5816x over previous
//
#include <hip/hip_runtime.h>

// Problem constants (match reference)
#define NF  200
#define DIN 3
#define NH  15
#define NE  30
#define NB  32768

constexpr int BT = 256;       // threads per block (4 waves)
constexpr int MB = 4;         // batch rows per thread -> block covers 1024 b
constexpr int FC = 5;         // consecutive features per block -> grid.y = 40
constexpr int BB = BT * MB;   // 1024 batch rows per block
constexpr int YW = FC * DIN;  // 15 floats of y per b per block

__device__ __forceinline__ float rdlane(float v, int lane) {
    return __int_as_float(__builtin_amdgcn_readlane(__float_as_int(v), lane));
}

__global__ void nn_init(float* __restrict__ out, const float* __restrict__ b3) {
    int i = blockIdx.x * 256 + threadIdx.x;
    if (i < NB) out[i] = b3[0];
}

__global__ __launch_bounds__(BT, 2)
void nn_main(const float* __restrict__ y,  const float* __restrict__ W1,
             const float* __restrict__ b1, const float* __restrict__ W2,
             const float* __restrict__ b2, const float* __restrict__ W3,
             float* __restrict__ out) {
    __shared__ float sy[BB * YW];   // 1024 * 15 * 4B = 60 KiB

    const int t  = threadIdx.x;
    const int l  = t & 63;
    const int b0 = blockIdx.x * BB;
    const int f0 = blockIdx.y * FC;

    // ---- stage y tile (coalesced: 60B contiguous per b-row) ----
    for (int idx = t; idx < BB * YW; idx += BT) {
        const int bb = idx / YW;
        const int k  = idx % YW;
        sy[idx] = y[(size_t)(b0 + bb) * (NF * DIN) + (size_t)f0 * DIN + k];
    }
    __syncthreads();

    float partial[MB];
#pragma unroll
    for (int m = 0; m < MB; ++m) partial[m] = 0.f;

#pragma unroll 1
    for (int fi = 0; fi < FC; ++fi) {
        const int f = f0 + fi;

        // ---- stage this feature's weights into per-lane VGPRs (coalesced) ----
        const float* __restrict__ W2f = W2 + (size_t)f * (NH * NE);
        float w2v[8];
#pragma unroll
        for (int r = 0; r < 8; ++r) {
            const int j = r * 64 + l;
            w2v[r] = (j < NH * NE) ? W2f[j] : 0.f;
        }
        const float w1v = (l < DIN * NH) ? W1[(size_t)f * (DIN * NH) + l] : 0.f;
        const float b1v = (l < NH) ? b1[f * NH + l] : 0.f;
        const float b2v = (l < NE) ? b2[f * NE + l] : 0.f;
        const float w3v = (l < NE) ? W3[f * NE + l] : 0.f;

        // ---- y for this feature from LDS (stride-15 -> 2-way, free) ----
        float yv[MB][DIN];
#pragma unroll
        for (int m = 0; m < MB; ++m) {
            const int base = (m * BT + t) * YW + fi * DIN;
            yv[m][0] = sy[base + 0];
            yv[m][1] = sy[base + 1];
            yv[m][2] = sy[base + 2];
        }

        // ---- layer 1: h1 = relu(y @ W1 + b1); weights via readlane->SGPR ----
        float h1[MB][NH];
#pragma unroll
        for (int h = 0; h < NH; ++h) {
            const float w0 = rdlane(w1v, 0 * NH + h);
            const float w1_ = rdlane(w1v, 1 * NH + h);
            const float w2_ = rdlane(w1v, 2 * NH + h);
            const float bb1 = rdlane(b1v, h);
#pragma unroll
            for (int m = 0; m < MB; ++m) {
                float v = bb1;
                v = fmaf(yv[m][0], w0, v);
                v = fmaf(yv[m][1], w1_, v);
                v = fmaf(yv[m][2], w2_, v);
                h1[m][h] = fmaxf(v, 0.f);
            }
        }

        // ---- layer 2 + layer 3, per output neuron e ----
#pragma unroll
        for (int e = 0; e < NE; ++e) {
            float acc[MB];
            const float bb2 = rdlane(b2v, e);
#pragma unroll
            for (int m = 0; m < MB; ++m) acc[m] = bb2;
#pragma unroll
            for (int h = 0; h < NH; ++h) {
                const int j = h * NE + e;
                const float w = rdlane(w2v[j >> 6], j & 63);
#pragma unroll
                for (int m = 0; m < MB; ++m) acc[m] = fmaf(h1[m][h], w, acc[m]);
            }
            const float w3 = rdlane(w3v, e);
#pragma unroll
            for (int m = 0; m < MB; ++m) {
                partial[m] = fmaf(fmaxf(acc[m], 0.f), w3, partial[m]);
            }
        }
    }

#pragma unroll
    for (int m = 0; m < MB; ++m) {
        atomicAdd(&out[b0 + m * BT + t], partial[m]);
    }
}

extern "C" void kernel_launch(void* const* d_in, const int* in_sizes, int n_in,
                              void* d_out, int out_size, void* d_ws, size_t ws_size,
                              hipStream_t stream) {
    const float* y  = (const float*)d_in[0];
    const float* W1 = (const float*)d_in[1];
    const float* b1 = (const float*)d_in[2];
    const float* W2 = (const float*)d_in[3];
    const float* b2 = (const float*)d_in[4];
    const float* W3 = (const float*)d_in[5];
    const float* b3 = (const float*)d_in[6];
    float* out = (float*)d_out;

    nn_init<<<dim3((NB + 255) / 256), dim3(256), 0, stream>>>(out, b3);
    nn_main<<<dim3(NB / BB, NF / FC), dim3(BT), 0, stream>>>(
        y, W1, b1, W2, b2, W3, out);
}

// Round 3
// 110.615 us; speedup vs baseline: 2.2421x; 1.4176x over previous
//
#include <hip/hip_runtime.h>

// Problem constants
#define NF  200
#define DIN 3
#define NH  15
#define NE  30
#define NB  32768

typedef __attribute__((ext_vector_type(8))) short  short8;
typedef __attribute__((ext_vector_type(4))) float  f32x4;

// ws layout (byte offsets, all 256B-aligned):
// W1r : [NF][16][4] f32  {w0,w1,w2,b1} per h (pad h=15 -> 0)   @ 0       (51200 B)
// W2p : [NF][32][16] bf16  [e][k] transposed, zero-padded      @ 51200   (204800 B)
// b2p : [NF][32] f32 padded                                    @ 256000  (25600 B)
// w3p : [NF][32] f32 padded                                    @ 281600  (25600 B)
constexpr size_t OFF_W1R = 0;
constexpr size_t OFF_W2P = 51200;
constexpr size_t OFF_B2P = 256000;
constexpr size_t OFF_W3P = 281600;

constexpr int FSPLIT = 4;            // feature split across grid.y
constexpr int FPW    = NF / FSPLIT;  // 50 features per wave
constexpr int RPW    = 32;           // rows per wave (2 MFMA tiles of 16)
constexpr int RPB    = 4 * RPW;      // rows per block (4 waves)

__device__ __forceinline__ unsigned short f2bf(float x) {
    unsigned u = __float_as_uint(x);
    return (unsigned short)((u + 0x7FFFu + ((u >> 16) & 1u)) >> 16);
}

__global__ void nn_init(float* __restrict__ out, const float* __restrict__ b3) {
    int i = blockIdx.x * 256 + threadIdx.x;
    if (i < NB) out[i] = b3[0];
}

__global__ void nn_prep(const float* __restrict__ W1, const float* __restrict__ b1,
                        const float* __restrict__ W2, const float* __restrict__ b2,
                        const float* __restrict__ W3, char* __restrict__ ws) {
    const int f = blockIdx.x;
    const int t = threadIdx.x;
    float*          W1r = (float*)(ws + OFF_W1R);
    unsigned short* W2p = (unsigned short*)(ws + OFF_W2P);
    float*          b2p = (float*)(ws + OFF_B2P);
    float*          w3p = (float*)(ws + OFF_W3P);

    if (t < 16) {
        const int h = t;
        float w0 = 0.f, w1 = 0.f, w2 = 0.f, bb = 0.f;
        if (h < NH) {
            w0 = W1[f * DIN * NH + 0 * NH + h];
            w1 = W1[f * DIN * NH + 1 * NH + h];
            w2 = W1[f * DIN * NH + 2 * NH + h];
            bb = b1[f * NH + h];
        }
        float* dst = W1r + (size_t)(f * 16 + h) * 4;
        dst[0] = w0; dst[1] = w1; dst[2] = w2; dst[3] = bb;
    }
    for (int idx = t; idx < 512; idx += 64) {
        const int e = idx >> 4, k = idx & 15;
        const float v = (e < NE && k < NH) ? W2[(size_t)f * NH * NE + k * NE + e] : 0.f;
        W2p[(size_t)f * 512 + idx] = f2bf(v);
    }
    if (t < 32) {
        b2p[f * 32 + t] = (t < NE) ? b2[f * NE + t] : 0.f;
        w3p[f * 32 + t] = (t < NE) ? W3[f * NE + t] : 0.f;
    }
}

__global__ __launch_bounds__(256, 4)
void nn_main(const float* __restrict__ y, const char* __restrict__ ws,
             float* __restrict__ out) {
    const float* __restrict__ W1r = (const float*)(ws + OFF_W1R);
    const short* __restrict__ W2p = (const short*)(ws + OFF_W2P);
    const float* __restrict__ b2p = (const float*)(ws + OFF_B2P);
    const float* __restrict__ w3p = (const float*)(ws + OFF_W3P);

    const int t  = threadIdx.x;
    const int w  = t >> 6;
    const int l  = t & 63;
    const int lr = l & 15;   // row-in-tile (A), e-slot (B/C)
    const int lg = l >> 4;   // k-group
    const int r0 = blockIdx.x * RPB + w * RPW;
    const int f0 = blockIdx.y * FPW;

    f32x4 acc0 = {0.f, 0.f, 0.f, 0.f};
    f32x4 acc1 = {0.f, 0.f, 0.f, 0.f};

    const float* __restrict__ y0p = y + (size_t)(r0 + lr)      * (NF * DIN);
    const float* __restrict__ y1p = y + (size_t)(r0 + 16 + lr) * (NF * DIN);

#pragma unroll 1
    for (int f = f0; f < f0 + FPW; ++f) {
        // ---- layer 1 directly in A-fragment layout (fp32 VALU, then bf16) ----
        short8 a0 = {0,0,0,0,0,0,0,0};
        short8 a1 = {0,0,0,0,0,0,0,0};
        short8 bf0 = {0,0,0,0,0,0,0,0};
        short8 bf1 = {0,0,0,0,0,0,0,0};
        if (lg < 2) {
            const float* __restrict__ wp = W1r + (size_t)(f * 16 + lg * 8) * 4;
            const float ya0 = y0p[f * 3 + 0], ya1 = y0p[f * 3 + 1], ya2 = y0p[f * 3 + 2];
            const float yb0 = y1p[f * 3 + 0], yb1 = y1p[f * 3 + 1], yb2 = y1p[f * 3 + 2];
#pragma unroll
            for (int j = 0; j < 8; ++j) {
                const float w0 = wp[j * 4 + 0], w1 = wp[j * 4 + 1];
                const float w2 = wp[j * 4 + 2], bb = wp[j * 4 + 3];
                float v0 = fmaf(ya0, w0, fmaf(ya1, w1, fmaf(ya2, w2, bb)));
                float v1 = fmaf(yb0, w0, fmaf(yb1, w1, fmaf(yb2, w2, bb)));
                a0[j] = (short)f2bf(fmaxf(v0, 0.f));
                a1[j] = (short)f2bf(fmaxf(v1, 0.f));
            }
            // ---- B fragments: one 16B load each (repacked bf16 [e][k]) ----
            bf0 = *(const short8*)(W2p + ((size_t)(f * 32 +      lr) * 16 + lg * 8));
            bf1 = *(const short8*)(W2p + ((size_t)(f * 32 + 16 + lr) * 16 + lg * 8));
        }

        const float cb0 = b2p[f * 32 + lr];
        const float cb1 = b2p[f * 32 + 16 + lr];
        const float w30 = w3p[f * 32 + lr];
        const float w31 = w3p[f * 32 + 16 + lr];
        const f32x4 c0 = {cb0, cb0, cb0, cb0};
        const f32x4 c1 = {cb1, cb1, cb1, cb1};

        const f32x4 d00 = __builtin_amdgcn_mfma_f32_16x16x32_bf16(a0, bf0, c0, 0, 0, 0);
        const f32x4 d01 = __builtin_amdgcn_mfma_f32_16x16x32_bf16(a0, bf1, c1, 0, 0, 0);
        const f32x4 d10 = __builtin_amdgcn_mfma_f32_16x16x32_bf16(a1, bf0, c0, 0, 0, 0);
        const f32x4 d11 = __builtin_amdgcn_mfma_f32_16x16x32_bf16(a1, bf1, c1, 0, 0, 0);

#pragma unroll
        for (int r = 0; r < 4; ++r) {
            acc0[r] += fmaxf(d00[r], 0.f) * w30 + fmaxf(d01[r], 0.f) * w31;
            acc1[r] += fmaxf(d10[r], 0.f) * w30 + fmaxf(d11[r], 0.f) * w31;
        }
    }

    // ---- reduce over the 16 e-slots (lanes lr=0..15 within each group) ----
#pragma unroll
    for (int r = 0; r < 4; ++r) {
#pragma unroll
        for (int m = 1; m < 16; m <<= 1) {
            acc0[r] += __shfl_xor(acc0[r], m, 16);
            acc1[r] += __shfl_xor(acc1[r], m, 16);
        }
    }
    if (lr == 0) {
#pragma unroll
        for (int r = 0; r < 4; ++r) {
            atomicAdd(&out[r0 +      lg * 4 + r], acc0[r]);
            atomicAdd(&out[r0 + 16 + lg * 4 + r], acc1[r]);
        }
    }
}

extern "C" void kernel_launch(void* const* d_in, const int* in_sizes, int n_in,
                              void* d_out, int out_size, void* d_ws, size_t ws_size,
                              hipStream_t stream) {
    const float* y  = (const float*)d_in[0];
    const float* W1 = (const float*)d_in[1];
    const float* b1 = (const float*)d_in[2];
    const float* W2 = (const float*)d_in[3];
    const float* b2 = (const float*)d_in[4];
    const float* W3 = (const float*)d_in[5];
    const float* b3 = (const float*)d_in[6];
    float* out = (float*)d_out;

    nn_prep<<<dim3(NF), dim3(64), 0, stream>>>(W1, b1, W2, b2, W3, (char*)d_ws);
    nn_init<<<dim3((NB + 255) / 256), dim3(256), 0, stream>>>(out, b3);
    nn_main<<<dim3(NB / RPB, FSPLIT), dim3(256), 0, stream>>>(
        y, (const char*)d_ws, out);
}

// Round 4
// 95.431 us; speedup vs baseline: 2.5989x; 1.1591x over previous
//
#include <hip/hip_runtime.h>
#include <hip/hip_bf16.h>

// Problem constants
#define NF  200
#define DIN 3
#define NH  15
#define NE  30
#define NB  32768

typedef __attribute__((ext_vector_type(8)))  short short8;
typedef __attribute__((ext_vector_type(16))) float f32x16;
typedef __attribute__((ext_vector_type(2)))  float f32x2;

// ws layout (byte offsets):
// W1r : [NF][16][4] f32  {w0,w1,w2,b1} per h, h=15 zeroed        @ 0       (51200 B)
// W2q : [NF][64][8] bf16  exact B-fragment order for 32x32x16:   @ 51200   (204800 B)
//        lane l, slot j ->  B[k=(l>>5)*8+j][e=l&31], zero-padded
// BW3 : [NF][32][2] f32  {b2[e], W3[e]} interleaved, e>=30 -> 0  @ 256000  (51200 B)
constexpr size_t OFF_W1R = 0;
constexpr size_t OFF_W2Q = 51200;
constexpr size_t OFF_BW3 = 256000;

constexpr int FSPLIT = 8;            // feature split across grid.y
constexpr int FPW    = NF / FSPLIT;  // 25 features per wave
constexpr int RPW    = 32;           // rows per wave (one 32x32 MFMA tile)
constexpr int RPB    = 4 * RPW;      // 128 rows per block

__device__ __forceinline__ unsigned short f2bf(float x) {
    __hip_bfloat16 h = __float2bfloat16(x);
    unsigned short u;
    __builtin_memcpy(&u, &h, 2);
    return u;
}

__global__ void nn_init(float* __restrict__ out, const float* __restrict__ b3) {
    int i = blockIdx.x * 256 + threadIdx.x;
    if (i < NB) out[i] = b3[0];
}

__global__ void nn_prep(const float* __restrict__ W1, const float* __restrict__ b1,
                        const float* __restrict__ W2, const float* __restrict__ b2,
                        const float* __restrict__ W3, char* __restrict__ ws) {
    const int f = blockIdx.x;
    const int t = threadIdx.x;   // 64 threads
    float*          W1r = (float*)(ws + OFF_W1R);
    unsigned short* W2q = (unsigned short*)(ws + OFF_W2Q);
    float*          BW3 = (float*)(ws + OFF_BW3);

    if (t < 16) {
        const int h = t;
        float w0 = 0.f, w1 = 0.f, w2 = 0.f, bb = 0.f;
        if (h < NH) {
            w0 = W1[f * DIN * NH + 0 * NH + h];
            w1 = W1[f * DIN * NH + 1 * NH + h];
            w2 = W1[f * DIN * NH + 2 * NH + h];
            bb = b1[f * NH + h];
        }
        float* dst = W1r + (size_t)(f * 16 + h) * 4;
        dst[0] = w0; dst[1] = w1; dst[2] = w2; dst[3] = bb;
    }
    // W2 in exact B-fragment order: lane t, slot j -> B[k=(t>>5)*8+j][e=t&31]
#pragma unroll
    for (int j = 0; j < 8; ++j) {
        const int k = (t >> 5) * 8 + j;
        const int e = t & 31;
        const float v = (k < NH && e < NE) ? W2[(size_t)f * (NH * NE) + k * NE + e] : 0.f;
        W2q[(size_t)f * 512 + t * 8 + j] = f2bf(v);
    }
    if (t < 32) {
        BW3[(size_t)f * 64 + t * 2 + 0] = (t < NE) ? b2[f * NE + t] : 0.f;
        BW3[(size_t)f * 64 + t * 2 + 1] = (t < NE) ? W3[f * NE + t] : 0.f;
    }
}

__global__ __launch_bounds__(256, 4)
void nn_main(const float* __restrict__ y, const char* __restrict__ ws,
             float* __restrict__ out) {
    const float* __restrict__ W1r = (const float*)(ws + OFF_W1R);
    const short* __restrict__ W2q = (const short*)(ws + OFF_W2Q);
    const float* __restrict__ BW3 = (const float*)(ws + OFF_BW3);

    const int t  = threadIdx.x;
    const int w  = t >> 6;
    const int l  = t & 63;
    const int ln = l & 31;   // A row-in-tile; B/C e-column
    const int hi = l >> 5;   // k-group: h = hi*8 + j
    const int r0 = blockIdx.x * RPB + w * RPW;
    const int f0 = blockIdx.y * FPW;

    const float* __restrict__ yp = y + (size_t)(r0 + ln) * (NF * DIN) + (size_t)f0 * DIN;

    float acc[16];
#pragma unroll
    for (int r = 0; r < 16; ++r) acc[r] = 0.f;

#pragma unroll 2
    for (int fi = 0; fi < FPW; ++fi) {
        const int f = f0 + fi;

        // ---- layer 1: lane computes its own A-fragment slots (row ln, h=hi*8+j)
        const float* __restrict__ wp = W1r + ((size_t)f * 16 + hi * 8) * 4;
        const float y0 = yp[fi * 3 + 0];
        const float y1 = yp[fi * 3 + 1];
        const float y2 = yp[fi * 3 + 2];

        union { unsigned u[4]; short8 s; } A;
#pragma unroll
        for (int i = 0; i < 4; ++i) {
            const float* wa = wp + (2 * i) * 4;
            const float* wb = wp + (2 * i + 1) * 4;
            float va = fmaf(y0, wa[0], fmaf(y1, wa[1], fmaf(y2, wa[2], wa[3])));
            float vb = fmaf(y0, wb[0], fmaf(y1, wb[1], fmaf(y2, wb[2], wb[3])));
            va = fmaxf(va, 0.f);
            vb = fmaxf(vb, 0.f);
            A.u[i] = (unsigned)f2bf(va) | ((unsigned)f2bf(vb) << 16);
        }

        // ---- B fragment: one 16B load in exact fragment order
        const short8 B = *(const short8*)(W2q + (size_t)f * 512 + l * 8);

        // ---- C = b2[e] splat; W3[e] for epilogue
        const f32x2 bw = *(const f32x2*)(BW3 + (size_t)f * 64 + ln * 2);
        f32x16 c;
#pragma unroll
        for (int r = 0; r < 16; ++r) c[r] = bw.x;

        const f32x16 d = __builtin_amdgcn_mfma_f32_32x32x16_bf16(A.s, B, c, 0, 0, 0);

        // ---- epilogue: out-partial += relu(h2) * W3[e]
#pragma unroll
        for (int r = 0; r < 16; ++r) acc[r] = fmaf(fmaxf(d[r], 0.f), bw.y, acc[r]);
    }

    // ---- reduce over e (32 lanes within each half) ----
#pragma unroll
    for (int r = 0; r < 16; ++r) {
#pragma unroll
        for (int m = 1; m < 32; m <<= 1) acc[r] += __shfl_xor(acc[r], m);
    }
    if (ln == 0) {
#pragma unroll
        for (int r = 0; r < 16; ++r) {
            const int row = (r & 3) + 8 * (r >> 2) + 4 * hi;
            atomicAdd(&out[r0 + row], acc[r]);
        }
    }
}

extern "C" void kernel_launch(void* const* d_in, const int* in_sizes, int n_in,
                              void* d_out, int out_size, void* d_ws, size_t ws_size,
                              hipStream_t stream) {
    const float* y  = (const float*)d_in[0];
    const float* W1 = (const float*)d_in[1];
    const float* b1 = (const float*)d_in[2];
    const float* W2 = (const float*)d_in[3];
    const float* b2 = (const float*)d_in[4];
    const float* W3 = (const float*)d_in[5];
    const float* b3 = (const float*)d_in[6];
    float* out = (float*)d_out;

    nn_prep<<<dim3(NF), dim3(64), 0, stream>>>(W1, b1, W2, b2, W3, (char*)d_ws);
    nn_init<<<dim3((NB + 255) / 256), dim3(256), 0, stream>>>(out, b3);
    nn_main<<<dim3(NB / RPB, FSPLIT), dim3(256), 0, stream>>>(
        y, (const char*)d_ws, out);
}

// Round 5
// 59.381 us; speedup vs baseline: 4.1767x; 1.6071x over previous
//
#include <hip/hip_runtime.h>
#include <hip/hip_bf16.h>

// Problem constants
#define NF  200
#define DIN 3
#define NH  15
#define NE  30
#define NB  32768

typedef __attribute__((ext_vector_type(8)))  short short8;
typedef __attribute__((ext_vector_type(16))) float f32x16;

constexpr int FSPLIT = 10;           // feature split across grid.y
constexpr int FPW    = NF / FSPLIT;  // 20 features per wave
constexpr int FB     = 4;            // features per y-load batch (3 x float4)
constexpr int NBATCH = FPW / FB;     // 5
constexpr int RPW    = 32;           // rows per wave (one 32x32 MFMA tile)
constexpr int RPB    = 4 * RPW;      // 128 rows per block

// ws layout:
// A1q : [NF][64][4 bf16]  layer-1 A-frag (W1 hi/lo split + b1)   @ 0       (102400 B)
// W2q : [NF][64][8 bf16]  layer-2 B-frag, perm'd k-map, b2@k15   @ 102400  (204800 B)
// w3p : [NF][32] f32                                             @ 307200  (25600 B)
constexpr size_t OFF_A1Q = 0;
constexpr size_t OFF_W2Q = 102400;
constexpr size_t OFF_W3P = 307200;

__device__ __forceinline__ unsigned short f2bf(float x) {
    __hip_bfloat16 h = __float2bfloat16(x);
    unsigned short u; __builtin_memcpy(&u, &h, 2); return u;
}
__device__ __forceinline__ float bf2f(unsigned short u) {
    unsigned v = (unsigned)u << 16; float f; __builtin_memcpy(&f, &v, 4); return f;
}

__global__ void nn_init(float* __restrict__ out, const float* __restrict__ b3) {
    int i = blockIdx.x * 256 + threadIdx.x;
    if (i < NB) out[i] = b3[0];
}

__global__ void nn_prep(const float* __restrict__ W1, const float* __restrict__ b1,
                        const float* __restrict__ W2, const float* __restrict__ b2,
                        const float* __restrict__ W3, char* __restrict__ ws) {
    const int f = blockIdx.x;
    const int t = threadIdx.x;       // 64
    const int x = t & 31, hi = t >> 5;
    unsigned short* A1q = (unsigned short*)(ws + OFF_A1Q);
    unsigned short* W2q = (unsigned short*)(ws + OFF_W2Q);
    float*          w3p = (float*)(ws + OFF_W3P);

    // ---- A1 fragment: lane x<16 rows hold W1; hi=0 -> hi-parts, hi=1 -> lo-parts
    {
        float w0 = 0.f, w1 = 0.f, w2 = 0.f, bb = 0.f;
        if (x < NH) {
            w0 = W1[((size_t)f * DIN + 0) * NH + x];
            w1 = W1[((size_t)f * DIN + 1) * NH + x];
            w2 = W1[((size_t)f * DIN + 2) * NH + x];
            bb = b1[f * NH + x];
        }
        unsigned short s0, s1, s2, s3;
        if (hi == 0) { s0 = f2bf(w0); s1 = f2bf(w1); s2 = f2bf(w2); s3 = f2bf(bb); }
        else {
            s0 = f2bf(w0 - bf2f(f2bf(w0)));
            s1 = f2bf(w1 - bf2f(f2bf(w1)));
            s2 = f2bf(w2 - bf2f(f2bf(w2)));
            s3 = 0;
        }
        unsigned short* d = A1q + ((size_t)f * 64 + t) * 4;
        d[0] = s0; d[1] = s1; d[2] = s2; d[3] = s3;
    }
    // ---- W2 B-fragment with permuted k-map; h==15 slot carries b2
    {
        const int e = x;
        unsigned short* d = W2q + ((size_t)f * 64 + t) * 8;
#pragma unroll
        for (int j = 0; j < 8; ++j) {
            const int h = (j & 3) + 8 * (j >> 2) + 4 * hi;   // 0..15
            float v = 0.f;
            if (e < NE) v = (h < NH) ? W2[((size_t)f * NH + h) * NE + e]
                                     : b2[f * NE + e];       // h==15
            d[j] = f2bf(v);
        }
    }
    if (t < 32) w3p[f * 32 + t] = (t < NE) ? W3[f * NE + t] : 0.f;
}

__global__ __launch_bounds__(256, 4)
void nn_main(const float* __restrict__ y, const char* __restrict__ ws,
             float* __restrict__ out) {
    const unsigned short* __restrict__ A1q = (const unsigned short*)(ws + OFF_A1Q);
    const unsigned short* __restrict__ W2q = (const unsigned short*)(ws + OFF_W2Q);
    const float* __restrict__ w3p = (const float*)(ws + OFF_W3P);

    const int t  = threadIdx.x;
    const int w  = t >> 6;
    const int l  = t & 63;
    const int ln = l & 31;
    const int hi = l >> 5;
    const int r0 = blockIdx.x * RPB + w * RPW;
    const int f0 = blockIdx.y * FPW;

    const float* __restrict__ yrow =
        y + (size_t)(r0 + ln) * (NF * DIN) + (size_t)f0 * DIN;

    float acc[16];
#pragma unroll
    for (int r = 0; r < 16; ++r) acc[r] = 0.f;
    const f32x16 zc = {};   // zero C operand (b2 folded into k15)

#pragma unroll 1
    for (int bi = 0; bi < NBATCH; ++bi) {
        // ---- batched, aligned y loads: 12 floats = 4 features ----
        const float4* yp = reinterpret_cast<const float4*>(yrow + bi * (FB * DIN));
        const float4 v0 = yp[0], v1 = yp[1], v2 = yp[2];
        const float ya[12] = {v0.x, v0.y, v0.z, v0.w,
                              v1.x, v1.y, v1.z, v1.w,
                              v2.x, v2.y, v2.z, v2.w};

#pragma unroll
        for (int ff = 0; ff < FB; ++ff) {
            const int f = f0 + bi * FB + ff;
            const float y0 = ya[ff * 3 + 0];
            const float y1 = ya[ff * 3 + 1];
            const float y2 = ya[ff * 3 + 2];

            // ---- B1 fragment: y split hi/lo, bias-one at k3 ----
            const unsigned short yh0 = f2bf(y0), yh1 = f2bf(y1), yh2 = f2bf(y2);
            const unsigned short yl0 = f2bf(y0 - bf2f(yh0));
            const unsigned short yl1 = f2bf(y1 - bf2f(yh1));
            const unsigned short yl2 = f2bf(y2 - bf2f(yh2));
            union { unsigned u[4]; short8 s; } B1;
            B1.u[0] = (unsigned)yh0 | ((unsigned)yh1 << 16);
            B1.u[1] = (unsigned)yh2 | (hi ? 0u : 0x3F800000u);
            B1.u[2] = hi ? 0u : ((unsigned)yl0 | ((unsigned)yl1 << 16));
            B1.u[3] = hi ? 0u : (unsigned)yl2;

            // ---- A1 fragment: 8B load; k4..6 duplicate k0..2 in-register ----
            const uint2 a = *reinterpret_cast<const uint2*>(A1q + ((size_t)f * 64 + l) * 4);
            union { unsigned u[4]; short8 s; } A1;
            A1.u[0] = a.x;
            A1.u[1] = a.y;
            A1.u[2] = hi ? 0u : a.x;
            A1.u[3] = hi ? 0u : (a.y & 0xFFFFu);

            // ---- layer 1 on MFMA: D1[h][brow] ----
            const f32x16 d1 = __builtin_amdgcn_mfma_f32_32x32x16_bf16(A1.s, B1.s, zc, 0, 0, 0);

            // ---- A2 = relu(h1) in bf16, k-map = D1 reg perm; 1.0 at k15 ----
            unsigned short c[8];
#pragma unroll
            for (int j = 0; j < 8; ++j) c[j] = f2bf(fmaxf(d1[j], 0.f));
            union { unsigned u[4]; short8 s; } A2;
            A2.u[0] = (unsigned)c[0] | ((unsigned)c[1] << 16);
            A2.u[1] = (unsigned)c[2] | ((unsigned)c[3] << 16);
            A2.u[2] = (unsigned)c[4] | ((unsigned)c[5] << 16);
            A2.u[3] = ((unsigned)c[6] | ((unsigned)c[7] << 16)) | (hi ? 0x3F800000u : 0u);

            // ---- layer 2 on MFMA ----
            const short8 B2 = *reinterpret_cast<const short8*>(W2q + ((size_t)f * 64 + l) * 8);
            const f32x16 d2 = __builtin_amdgcn_mfma_f32_32x32x16_bf16(A2.s, B2, zc, 0, 0, 0);

            // ---- epilogue: acc += relu(h2) * W3[e] ----
            const float w3v = w3p[f * 32 + ln];
#pragma unroll
            for (int r = 0; r < 16; ++r) acc[r] = fmaf(fmaxf(d2[r], 0.f), w3v, acc[r]);
        }
    }

    // ---- reduce over e (32 lanes within each half) ----
#pragma unroll
    for (int r = 0; r < 16; ++r) {
#pragma unroll
        for (int m = 1; m < 32; m <<= 1) acc[r] += __shfl_xor(acc[r], m);
    }
    if (ln == 0) {
#pragma unroll
        for (int r = 0; r < 16; ++r) {
            const int row = (r & 3) + 8 * (r >> 2) + 4 * hi;
            atomicAdd(&out[r0 + row], acc[r]);
        }
    }
}

extern "C" void kernel_launch(void* const* d_in, const int* in_sizes, int n_in,
                              void* d_out, int out_size, void* d_ws, size_t ws_size,
                              hipStream_t stream) {
    const float* y  = (const float*)d_in[0];
    const float* W1 = (const float*)d_in[1];
    const float* b1 = (const float*)d_in[2];
    const float* W2 = (const float*)d_in[3];
    const float* b2 = (const float*)d_in[4];
    const float* W3 = (const float*)d_in[5];
    const float* b3 = (const float*)d_in[6];
    float* out = (float*)d_out;

    nn_prep<<<dim3(NF), dim3(64), 0, stream>>>(W1, b1, W2, b2, W3, (char*)d_ws);
    nn_init<<<dim3((NB + 255) / 256), dim3(256), 0, stream>>>(out, b3);
    nn_main<<<dim3(NB / RPB, FSPLIT), dim3(256), 0, stream>>>(
        y, (const char*)d_ws, out);
}